// Round 11
// baseline (23.659 us; speedup 1.0000x reference)
//
#include <hip/hip_runtime.h>
#include <hip/hip_bf16.h>

#define N_SHARD 4
#define PPP     512
#define NEG_N   1024
#define EMB     256
#define NROWS   (N_SHARD * PPP)   // 2048

typedef __attribute__((ext_vector_type(8))) short bf16x8;  // 8 bf16 (4 VGPRs)
typedef __attribute__((ext_vector_type(4))) float f32x4;   // 4 fp32 acc

__device__ __forceinline__ unsigned short f2bf(float f) {
    union { float f; unsigned int u; } v; v.f = f;
    return (unsigned short)((v.u + 0x7FFFu + ((v.u >> 16) & 1u)) >> 16);
}

// ONE kernel, no workspace, no cross-block dependency. Grid 512 x 256 threads
// (4 waves), 64x64 tiles, LDS 65 KB -> 2 blocks/CU: generation-2 gathers
// overlap generation-1 store drains on every CU (r10 was 1 block/CU with
// strictly serial gather->store phases).
// Block (p = bx&31, q = bx>>5): rows p*64..+64, cols q*64..+64.
// bx%8 == p%8 -> all 16 q-blocks sharing an A-panel live on one XCD (A
// fetched once per XCD into L2). q==0 blocks also produce positive scores.
// Each wave exclusively owns its 16 A-rows -> epilogue reuses its Abuf slice
// as transpose scratch with NO barrier.
__global__ __launch_bounds__(256, 2) void fused_kernel(
    const int* __restrict__ head, const int* __restrict__ relation,
    const int* __restrict__ tail, const int* __restrict__ negative,
    const float* __restrict__ ent, const float* __restrict__ relemb,
    float* __restrict__ pos_out, float* __restrict__ neg_out)
{
    __shared__ unsigned short Abuf[64 * EMB];    // 32 KiB, XOR-swizzled
    __shared__ unsigned short Bbuf[64 * EMB];    // 32 KiB, XOR-swizzled
    __shared__ int idxbuf[256];                  // h(64) r(64) n(64) t(64)

    const int tid  = threadIdx.x;
    const int wid  = tid >> 6;        // 0..3
    const int lane = tid & 63;
    const int p    = blockIdx.x & 31;
    const int q    = blockIdx.x >> 5; // 0..15
    const int row0 = p * 64;
    const int col0 = q * 64;

    int* hIdx = idxbuf;               // 64
    int* rIdx = idxbuf + 64;          // 64
    int* nIdx = idxbuf + 128;         // 64
    int* tIdx = idxbuf + 192;         // 64 (q==0 only)

    // ---- Phase 0: coalesced index preload ----
    if (tid < 64)       hIdx[tid]       = head[row0 + tid];
    else if (tid < 128) rIdx[tid - 64]  = relation[row0 + tid - 64];
    else if (tid < 192) nIdx[tid - 128] = negative[col0 + tid - 128]; // shard 0
    else if (q == 0)    tIdx[tid - 192] = tail[row0 + tid - 192];
    __syncthreads();

    // ---- Phase 1: A gather (wave w -> rows w*16..+16), hr -> bf16 LDS ----
    #pragma unroll
    for (int i = 0; i < 16; ++i) {
        const int r = wid * 16 + i;
        const float4 h4 = ((const float4*)(ent    + (size_t)hIdx[r] * EMB))[lane];
        const float4 r4 = ((const float4*)(relemb + (size_t)rIdx[r] * EMB))[lane];
        const float x = h4.x * r4.x, y = h4.y * r4.y;
        const float z = h4.z * r4.z, w = h4.w * r4.w;
        const ushort4 s = make_ushort4(f2bf(x), f2bf(y), f2bf(z), f2bf(w));
        *(ushort4*)((char*)Abuf + r * 512 + ((lane * 8) ^ ((r & 7) << 4))) = s;
        if (q == 0) {
            const float4 t4 = ((const float4*)(ent + (size_t)tIdx[r] * EMB))[lane];
            float pd = x * t4.x + y * t4.y + z * t4.z + w * t4.w;
            #pragma unroll
            for (int off = 32; off > 0; off >>= 1) pd += __shfl_down(pd, off, 64);
            if (lane == 0) pos_out[row0 + r] = pd;
        }
    }
    // ---- Phase 1b: B gather (wave w -> rows w*16..+16) ----
    #pragma unroll
    for (int i = 0; i < 16; ++i) {
        const int m = wid * 16 + i;
        const float4 t4 = ((const float4*)(ent + (size_t)nIdx[m] * EMB))[lane];
        const ushort4 s = make_ushort4(f2bf(t4.x), f2bf(t4.y), f2bf(t4.z), f2bf(t4.w));
        *(ushort4*)((char*)Bbuf + m * 512 + ((lane * 8) ^ ((m & 7) << 4))) = s;
    }
    __syncthreads();

    // ---- Phase 2: MFMA. wave wid: rows wid*16..+16 x all 64 cols ----
    const int r16  = lane & 15;
    const int half = lane >> 4;
    const int arow = wid * 16 + r16;
    const int aswz = (arow & 7) << 4;
    const int bswz = (r16 & 7) << 4;

    f32x4 acc[4];
    #pragma unroll
    for (int nf = 0; nf < 4; ++nf) acc[nf] = (f32x4){0.f, 0.f, 0.f, 0.f};

    #pragma unroll
    for (int kk = 0; kk < 8; ++kk) {
        const int koff = kk * 64 + half * 16;
        const bf16x8 a = *(const bf16x8*)((const char*)Abuf + arow * 512 + (koff ^ aswz));
        #pragma unroll
        for (int nf = 0; nf < 4; ++nf) {
            const bf16x8 b = *(const bf16x8*)((const char*)Bbuf + (nf * 16 + r16) * 512 + (koff ^ bswz));
            acc[nf] = __builtin_amdgcn_mfma_f32_16x16x32_bf16(a, b, acc[nf], 0, 0, 0);
        }
    }

    // ---- Epilogue: intra-wave LDS transpose through the wave's own (dead,
    //      exclusively-owned) A-slice — no barrier — then NT float4 stores ----
    float* cw = (float*)((char*)Abuf + wid * 8192);
    #pragma unroll
    for (int v = 0; v < 4; ++v) {
        const int lr = half * 4 + v;
        #pragma unroll
        for (int nf = 0; nf < 4; ++nf) {
            const int c = nf * 16 + r16;
            cw[lr * 64 + (c ^ (half << 4))] = acc[nf][v];
        }
    }
    #pragma unroll
    for (int j = 0; j < 4; ++j) {
        const int lr = j * 4 + half;
        const f32x4 v4 = *(const f32x4*)&cw[lr * 64 + ((r16 * 4) ^ (j << 4))];
        const int grow = row0 + wid * 16 + lr;
        float* orow = neg_out + (size_t)grow * 4096 + col0 + r16 * 4;
        __builtin_nontemporal_store(v4, (f32x4*)(orow));
        __builtin_nontemporal_store(v4, (f32x4*)(orow + 1024));
        __builtin_nontemporal_store(v4, (f32x4*)(orow + 2048));
        __builtin_nontemporal_store(v4, (f32x4*)(orow + 3072));
    }
}

extern "C" void kernel_launch(void* const* d_in, const int* in_sizes, int n_in,
                              void* d_out, int out_size, void* d_ws, size_t ws_size,
                              hipStream_t stream) {
    const int*   head     = (const int*)d_in[0];
    const int*   relation = (const int*)d_in[1];
    const int*   tail     = (const int*)d_in[2];
    const int*   negative = (const int*)d_in[3];
    const float* ent      = (const float*)d_in[4];
    const float* rel      = (const float*)d_in[5];

    float* pos_out = (float*)d_out;            // 2048
    float* neg_out = (float*)d_out + NROWS;    // 2048 * 4096

    fused_kernel<<<512, 256, 0, stream>>>(head, relation, tail, negative,
                                          ent, rel, pos_out, neg_out);
}

// Round 12
// 18.515 us; speedup vs baseline: 1.2779x; 1.2779x over previous
//
#include <hip/hip_runtime.h>
#include <hip/hip_bf16.h>

#define N_SHARD 4
#define PPP     512
#define NEG_N   1024
#define EMB     256
#define NROWS   (N_SHARD * PPP)   // 2048

typedef __attribute__((ext_vector_type(8))) short bf16x8;  // 8 bf16 (4 VGPRs)
typedef __attribute__((ext_vector_type(4))) float f32x4;   // 4 fp32 acc

__device__ __forceinline__ unsigned short f2bf(float f) {
    union { float f; unsigned int u; } v; v.f = f;
    return (unsigned short)((v.u + 0x7FFFu + ((v.u >> 16) & 1u)) >> 16);
}

// async 16B global->LDS copy (linear dest: wave-uniform base + lane*16)
__device__ __forceinline__ void load16_to_lds(const void* g, void* l) {
    __builtin_amdgcn_global_load_lds(
        (const __attribute__((address_space(1))) unsigned int*)g,
        (__attribute__((address_space(3))) unsigned int*)l, 16, 0, 0);
}

// ---------------- Kernel 1: balanced gather + positives + swizzled staging -------
// 256 blocks x 256 thr; wave gw does 3 row-tasks: hr rows gw, gw+1024, neg gw.
// Unique gather ~5.2 MB (vs 64 MB when every GEMM block re-gathers — r11 showed
// gather runs at HBM rate because the harness's 1 GB fills thrash L3).
// Staging rows are 512 B, XOR-swizzled by ((row&7)<<4) so the GEMM's
// ds_read_b128 after a LINEAR global_load_lds copy is conflict-free.
__global__ __launch_bounds__(256) void prep_kernel(
    const int* __restrict__ head, const int* __restrict__ relation,
    const int* __restrict__ tail, const int* __restrict__ negative,
    const float* __restrict__ ent, const float* __restrict__ relemb,
    float* __restrict__ pos_out,
    unsigned short* __restrict__ hr_bf, unsigned short* __restrict__ t_bf)
{
    const int wid  = threadIdx.x >> 6;
    const int lane = threadIdx.x & 63;
    const int gw   = blockIdx.x * 4 + wid;     // 0..1023

    #pragma unroll
    for (int rep = 0; rep < 2; ++rep) {
        const int n = gw + rep * 1024;
        const int hi = head[n], ri = relation[n], ti = tail[n];
        const float4 h4 = ((const float4*)(ent    + (size_t)hi * EMB))[lane];
        const float4 r4 = ((const float4*)(relemb + (size_t)ri * EMB))[lane];
        const float4 t4 = ((const float4*)(ent    + (size_t)ti * EMB))[lane];
        const float x = h4.x * r4.x, y = h4.y * r4.y;
        const float z = h4.z * r4.z, w = h4.w * r4.w;
        const ushort4 s = make_ushort4(f2bf(x), f2bf(y), f2bf(z), f2bf(w));
        const int byte_in_row = (lane * 8) ^ ((n & 7) << 4);
        *(ushort4*)((char*)hr_bf + (size_t)n * 512 + byte_in_row) = s;
        float p = x * t4.x + y * t4.y + z * t4.z + w * t4.w;
        #pragma unroll
        for (int off = 32; off > 0; off >>= 1) p += __shfl_down(p, off, 64);
        if (lane == 0) pos_out[n] = p;
    }
    {
        const int m = gw;
        const int idx = negative[m];   // negative[0][0][m]: only shard 0 used
        const float4 t4 = ((const float4*)(ent + (size_t)idx * EMB))[lane];
        const ushort4 s = make_ushort4(f2bf(t4.x), f2bf(t4.y), f2bf(t4.z), f2bf(t4.w));
        const int byte_in_row = (lane * 8) ^ ((m & 7) << 4);
        *(ushort4*)((char*)t_bf + (size_t)m * 512 + byte_in_row) = s;
    }
}

// ---------------- Kernel 2: 64x128 col-pair GEMM from staged operands -----------
// 256 blocks x 512 thr (8 waves), 96 KB LDS. Block (p = bx&31, cp = bx>>5):
// rows p*64..+64 x cols cp*128..+128. bx&31 mapping puts all 8 blocks of an
// A-panel on one XCD -> A staged-read is L2-hit after first touch. Phase-2
// math/epilogue is r10's proven code verbatim (8-wave wr/wc split).
__global__ __launch_bounds__(512, 1) void gemm_kernel(
    const unsigned short* __restrict__ hr_bf,
    const unsigned short* __restrict__ t_bf,
    float* __restrict__ neg_out)
{
    __shared__ unsigned short Abuf[64 * EMB];    // 32 KiB
    __shared__ unsigned short Bbuf[128 * EMB];   // 64 KiB

    const int wid  = threadIdx.x >> 6;   // 0..7
    const int lane = threadIdx.x & 63;
    const int row0 = (blockIdx.x & 31) * 64;
    const int col0 = (blockIdx.x >> 5) * 128;

    // Stage (linear dest; content pre-swizzled by prep, keyed by global row&7;
    // row0/col0 are multiples of 64 so local row&7 == global row&7).
    const char* aSrc = (const char*)(hr_bf + (size_t)row0 * EMB);
    const char* bSrc = (const char*)(t_bf  + (size_t)col0 * EMB);
    #pragma unroll
    for (int c = 0; c < 4; ++c) {
        const int chunk = (wid * 4 + c) * 1024;
        load16_to_lds(aSrc + chunk + lane * 16, (char*)Abuf + chunk);
    }
    #pragma unroll
    for (int c = 0; c < 8; ++c) {
        const int chunk = (wid * 8 + c) * 1024;
        load16_to_lds(bSrc + chunk + lane * 16, (char*)Bbuf + chunk);
    }
    __syncthreads();

    // ---- MFMA: wave (wr = wid>>1, wc = wid&1): rows wr*16..+16 x cols wc*64..+64
    const int r16  = lane & 15;
    const int half = lane >> 4;
    const int wr   = wid >> 1, wc = wid & 1;
    const int arow = wr * 16 + r16;
    const int aswz = (arow & 7) << 4;
    const int bb   = wc * 64;
    const int bswz = (r16 & 7) << 4;

    f32x4 acc[4];
    #pragma unroll
    for (int nf = 0; nf < 4; ++nf) acc[nf] = (f32x4){0.f, 0.f, 0.f, 0.f};

    #pragma unroll
    for (int kk = 0; kk < 8; ++kk) {
        const int koff = kk * 64 + half * 16;
        const bf16x8 a = *(const bf16x8*)((const char*)Abuf + arow * 512 + (koff ^ aswz));
        #pragma unroll
        for (int nf = 0; nf < 4; ++nf) {
            const bf16x8 b = *(const bf16x8*)((const char*)Bbuf + (bb + nf * 16 + r16) * 512 + (koff ^ bswz));
            acc[nf] = __builtin_amdgcn_mfma_f32_16x16x32_bf16(a, b, acc[nf], 0, 0, 0);
        }
    }
    __syncthreads();   // A-rows shared by two col-waves: all MFMAs done before scratch reuse

    // ---- Epilogue (r10 verbatim): intra-wave LDS transpose in the dead Abuf,
    //      4 KB slice per wave, then coalesced NT float4 stores x4 replicas ----
    float* cw = (float*)((char*)Abuf + wid * 4096);
    #pragma unroll
    for (int v = 0; v < 4; ++v) {
        const int lr = half * 4 + v;
        #pragma unroll
        for (int nf = 0; nf < 4; ++nf) {
            const int c = nf * 16 + r16;
            cw[lr * 64 + (c ^ (half << 4))] = acc[nf][v];
        }
    }
    #pragma unroll
    for (int j = 0; j < 4; ++j) {
        const int lr = j * 4 + half;
        const f32x4 v4 = *(const f32x4*)&cw[lr * 64 + ((r16 * 4) ^ (j << 4))];
        const int grow = row0 + wr * 16 + lr;
        float* orow = neg_out + (size_t)grow * 4096 + col0 + wc * 64 + r16 * 4;
        __builtin_nontemporal_store(v4, (f32x4*)(orow));
        __builtin_nontemporal_store(v4, (f32x4*)(orow + 1024));
        __builtin_nontemporal_store(v4, (f32x4*)(orow + 2048));
        __builtin_nontemporal_store(v4, (f32x4*)(orow + 3072));
    }
}

extern "C" void kernel_launch(void* const* d_in, const int* in_sizes, int n_in,
                              void* d_out, int out_size, void* d_ws, size_t ws_size,
                              hipStream_t stream) {
    const int*   head     = (const int*)d_in[0];
    const int*   relation = (const int*)d_in[1];
    const int*   tail     = (const int*)d_in[2];
    const int*   negative = (const int*)d_in[3];
    const float* ent      = (const float*)d_in[4];
    const float* rel      = (const float*)d_in[5];

    float* pos_out = (float*)d_out;            // 2048
    float* neg_out = (float*)d_out + NROWS;    // 2048 * 4096

    unsigned short* hr_bf = (unsigned short*)d_ws;                  // 1 MiB
    unsigned short* t_bf  = hr_bf + (size_t)NROWS * EMB;            // 0.5 MiB

    prep_kernel<<<256, 256, 0, stream>>>(head, relation, tail, negative,
                                         ent, rel, pos_out, hr_bf, t_bf);
    gemm_kernel<<<256, 512, 0, stream>>>(hr_bf, t_bf, neg_out);
}